// Round 4
// baseline (514.526 us; speedup 1.0000x reference)
//
#include <hip/hip_runtime.h>

#define MEDNUM 50000
#define FEATDIM 128
#define NNZ 3200000
#define NROWS (2 * MEDNUM)
#define NSLICE 8
#define SLICE_ROWS (NROWS / NSLICE)          // 12500 rows per XCD slice
#define SCAN_CHUNK 1024
#define NB ((NROWS + SCAN_CHUNK - 1) / SCAN_CHUNK)   // 98

// ws layout (4-byte words):
//   row_ptr : [0, 100352)
//   cursor  : [100352, 200704)
//   blk_sums: [200704, 200832)
//   bt      : [200832, 3400832)    bf16 table, 50000*128*2B = 12.8 MB
//   sorted  : [3400832, 9800832)   NNZ int2 = 25.6 MB (8B-aligned)
#define OFF_ROWPTR 0
#define OFF_CURSOR 100352
#define OFF_BLKSUM 200704
#define OFF_BT     200832
#define OFF_SORTED 3400832

// ---------------------------------------------------------------------------
// 0) fp32 -> packed bf16 (RNE) conversion of the embedding table
// ---------------------------------------------------------------------------
__global__ void tobf16_kernel(const float2* __restrict__ in, unsigned int* __restrict__ out) {
    int i = blockIdx.x * blockDim.x + threadIdx.x;
    const int n = MEDNUM * FEATDIM / 2;
    if (i >= n) return;
    float2 f = in[i];
    unsigned int a = __float_as_uint(f.x);
    unsigned int b = __float_as_uint(f.y);
    a = (a + 0x7fffu + ((a >> 16) & 1u)) >> 16;
    b = (b + 0x7fffu + ((b >> 16) & 1u)) >> 16;
    out[i] = a | (b << 16);
}

// ---------------------------------------------------------------------------
// 1) histogram of row_idx (row_idx is stream-once: non-temporal)
// ---------------------------------------------------------------------------
__global__ void hist_kernel(const int* __restrict__ row_idx, int* __restrict__ counts) {
    int e = blockIdx.x * blockDim.x + threadIdx.x;
    if (e < NNZ) {
        int r = __builtin_nontemporal_load(row_idx + e);
        atomicAdd(&counts[r], 1);
    }
}

// ---------------------------------------------------------------------------
// 2a) per-block exclusive scan, emit block sums
// ---------------------------------------------------------------------------
__global__ void scan1_kernel(int* __restrict__ row_ptr, int* __restrict__ blk_sums) {
    __shared__ int lds[256];
    int b = blockIdx.x, t = threadIdx.x;
    int base = b * SCAN_CHUNK + t * 4;
    int v0 = 0, v1 = 0, v2 = 0, v3 = 0;
    if (base + 0 < NROWS) v0 = row_ptr[base + 0];
    if (base + 1 < NROWS) v1 = row_ptr[base + 1];
    if (base + 2 < NROWS) v2 = row_ptr[base + 2];
    if (base + 3 < NROWS) v3 = row_ptr[base + 3];
    int s = v0 + v1 + v2 + v3;
    lds[t] = s;
    __syncthreads();
    for (int off = 1; off < 256; off <<= 1) {
        int x = 0;
        if (t >= off) x = lds[t - off];
        __syncthreads();
        if (t >= off) lds[t] += x;
        __syncthreads();
    }
    if (t == 255) blk_sums[b] = lds[255];
    int run = lds[t] - s;
    if (base + 0 < NROWS) row_ptr[base + 0] = run;  run += v0;
    if (base + 1 < NROWS) row_ptr[base + 1] = run;  run += v1;
    if (base + 2 < NROWS) row_ptr[base + 2] = run;  run += v2;
    if (base + 3 < NROWS) row_ptr[base + 3] = run;
}

// ---------------------------------------------------------------------------
// 2b) scan block sums (single block, NB=98 <= 128)
// ---------------------------------------------------------------------------
__global__ void scan2_kernel(int* __restrict__ blk_sums) {
    __shared__ int lds[128];
    int t = threadIdx.x;
    int v = (t < NB) ? blk_sums[t] : 0;
    lds[t] = v;
    __syncthreads();
    for (int off = 1; off < 128; off <<= 1) {
        int x = 0;
        if (t >= off) x = lds[t - off];
        __syncthreads();
        if (t >= off) lds[t] += x;
        __syncthreads();
    }
    if (t < NB) blk_sums[t] = lds[t] - v;
}

// ---------------------------------------------------------------------------
// 2c) add block offsets; init cursors
// ---------------------------------------------------------------------------
__global__ void scan3_kernel(int* __restrict__ row_ptr, int* __restrict__ cursor,
                             const int* __restrict__ blk_sums) {
    int i = blockIdx.x * blockDim.x + threadIdx.x;
    if (i < NROWS) {
        int p = row_ptr[i] + blk_sums[i / SCAN_CHUNK];
        row_ptr[i] = p;
        cursor[i] = p;
    }
    if (i == 0) row_ptr[NROWS] = NNZ;
}

// ---------------------------------------------------------------------------
// 3) XCD-sliced scatter with NON-TEMPORAL streaming reads: slice s = blockIdx%8
//    handles rows [s*12500,(s+1)*12500). nt loads keep the slice's 3.2 MB
//    write region resident in the XCD L2 so CSR lines fill before eviction.
// ---------------------------------------------------------------------------
#define SCAT_EPT 4
__global__ __launch_bounds__(256) void scatter_kernel(const float* __restrict__ vals,
                                                      const int* __restrict__ row_idx,
                                                      const int* __restrict__ col_idx,
                                                      int* __restrict__ cursor,
                                                      int2* __restrict__ sorted) {
    int slice = blockIdx.x & (NSLICE - 1);
    int tile  = blockIdx.x >> 3;
    int base  = tile * (256 * SCAT_EPT);
    int rlo = slice * SLICE_ROWS;
    int rhi = rlo + SLICE_ROWS;
#pragma unroll
    for (int k = 0; k < SCAT_EPT; k++) {
        int e = base + k * 256 + (int)threadIdx.x;
        if (e < NNZ) {
            int r = __builtin_nontemporal_load(row_idx + e);
            if (r >= rlo && r < rhi) {
                int c = __builtin_nontemporal_load(col_idx + e);
                if (c >= MEDNUM) c -= MEDNUM;
                float v = __builtin_nontemporal_load(vals + e);
                int pos = atomicAdd(&cursor[r], 1);
                sorted[pos] = make_int2(c, __float_as_int(v));
            }
        }
    }
}

// ---------------------------------------------------------------------------
// 4) aggregate: one wave per output row m; bf16 embed gathers (256B/edge).
//    `sorted` is stream-once -> non-temporal, so L2 keeps the bf16 table.
// ---------------------------------------------------------------------------
__device__ __forceinline__ void row_accum(const int* __restrict__ rp,
                                          const long long* __restrict__ sorted,
                                          const unsigned int* __restrict__ bt,
                                          int row, int lane, float& ax, float& ay) {
    int s = rp[row], e = rp[row + 1];
    int i = s;
    for (; i + 4 <= e; i += 4) {
        long long p0 = __builtin_nontemporal_load(sorted + i + 0);
        long long p1 = __builtin_nontemporal_load(sorted + i + 1);
        long long p2 = __builtin_nontemporal_load(sorted + i + 2);
        long long p3 = __builtin_nontemporal_load(sorted + i + 3);
        int c0 = (int)(p0 & 0xffffffffLL), c1 = (int)(p1 & 0xffffffffLL);
        int c2 = (int)(p2 & 0xffffffffLL), c3 = (int)(p3 & 0xffffffffLL);
        unsigned int w0 = bt[(long long)c0 * 64 + lane];
        unsigned int w1 = bt[(long long)c1 * 64 + lane];
        unsigned int w2 = bt[(long long)c2 * 64 + lane];
        unsigned int w3 = bt[(long long)c3 * 64 + lane];
        float v0 = __int_as_float((int)(p0 >> 32));
        float v1 = __int_as_float((int)(p1 >> 32));
        float v2 = __int_as_float((int)(p2 >> 32));
        float v3 = __int_as_float((int)(p3 >> 32));
        ax += v0 * __uint_as_float(w0 << 16);
        ay += v0 * __uint_as_float(w0 & 0xffff0000u);
        ax += v1 * __uint_as_float(w1 << 16);
        ay += v1 * __uint_as_float(w1 & 0xffff0000u);
        ax += v2 * __uint_as_float(w2 << 16);
        ay += v2 * __uint_as_float(w2 & 0xffff0000u);
        ax += v3 * __uint_as_float(w3 << 16);
        ay += v3 * __uint_as_float(w3 & 0xffff0000u);
    }
    for (; i < e; i++) {
        long long p = __builtin_nontemporal_load(sorted + i);
        int c = (int)(p & 0xffffffffLL);
        unsigned int w = bt[(long long)c * 64 + lane];
        float v = __int_as_float((int)(p >> 32));
        ax += v * __uint_as_float(w << 16);
        ay += v * __uint_as_float(w & 0xffff0000u);
    }
}

__global__ __launch_bounds__(256) void agg_kernel(const int* __restrict__ row_ptr,
                                                  const long long* __restrict__ sorted,
                                                  const unsigned int* __restrict__ bt,
                                                  const float* __restrict__ inter,
                                                  float* __restrict__ out) {
    int wave = (blockIdx.x * blockDim.x + threadIdx.x) >> 6;
    int lane = threadIdx.x & 63;
    if (wave >= MEDNUM) return;
    int m = wave;

    float a1x = 0.f, a1y = 0.f, a2x = 0.f, a2y = 0.f;
    row_accum(row_ptr, sorted, bt, m,          lane, a1x, a1y);
    row_accum(row_ptr, sorted, bt, m + MEDNUM, lane, a2x, a2y);

    float t = inter[0];
    float s1 = 2.f * t;
    float s2 = 2.f * (1.f - t);
    float2 o;
    o.x = s1 * fmaxf(a1x, 0.f) + s2 * fmaxf(a2x, 0.f);
    o.y = s1 * fmaxf(a1y, 0.f) + s2 * fmaxf(a2y, 0.f);
    *(float2*)(out + (long long)m * FEATDIM + lane * 2) = o;
}

extern "C" void kernel_launch(void* const* d_in, const int* in_sizes, int n_in,
                              void* d_out, int out_size, void* d_ws, size_t ws_size,
                              hipStream_t stream) {
    const float* vals    = (const float*)d_in[0];
    const float* mEmbed  = (const float*)d_in[1];
    const float* inter   = (const float*)d_in[2];
    const int*   row_idx = (const int*)d_in[3];
    const int*   col_idx = (const int*)d_in[4];
    float* out = (float*)d_out;

    int*  ws       = (int*)d_ws;
    int*  row_ptr  = ws + OFF_ROWPTR;
    int*  cursor   = ws + OFF_CURSOR;
    int*  blk_sums = ws + OFF_BLKSUM;
    unsigned int* bt = (unsigned int*)(ws + OFF_BT);
    int2* sorted   = (int2*)(ws + OFF_SORTED);

    tobf16_kernel<<<(MEDNUM * FEATDIM / 2 + 255) / 256, 256, 0, stream>>>(
        (const float2*)mEmbed, bt);
    hipMemsetAsync(row_ptr, 0, NROWS * sizeof(int), stream);
    hist_kernel<<<(NNZ + 255) / 256, 256, 0, stream>>>(row_idx, row_ptr);
    scan1_kernel<<<NB, 256, 0, stream>>>(row_ptr, blk_sums);
    scan2_kernel<<<1, 128, 0, stream>>>(blk_sums);
    scan3_kernel<<<(NROWS + 255) / 256, 256, 0, stream>>>(row_ptr, cursor, blk_sums);
    {
        int tiles = (NNZ + 256 * SCAT_EPT - 1) / (256 * SCAT_EPT);   // 3125
        scatter_kernel<<<tiles * NSLICE, 256, 0, stream>>>(vals, row_idx, col_idx, cursor, sorted);
    }
    agg_kernel<<<(MEDNUM * 64 + 255) / 256, 256, 0, stream>>>(
        row_ptr, (const long long*)sorted, bt, inter, out);
}

// Round 5
// 312.425 us; speedup vs baseline: 1.6469x; 1.6469x over previous
//
#include <hip/hip_runtime.h>

#define MEDNUM 50000
#define FEATDIM 128
#define NNZ 3200000
#define NROWS 100000
#define NBUCK 782              // ceil(50000/64) buckets of 64 folded rows
#define PART_BLOCKS 256
#define PART_N 12500           // NNZ / PART_BLOCKS (exact)
#define PART_K 13              // ceil(12500/1024)
#define SORT_CAP 5120
#define SORT_K 20              // SORT_K*256 = 5120 >= max bucket size (E=4096, sigma=64)

// ws layout (4-byte words):
#define OFF_CNTB   0           // [0,800)       bucket histogram (782)
#define OFF_BASE   800         // [800,1600)    bucket base (783)
#define OFF_CUR    1600        // [1600,2400)   global cursors (782)
#define OFF_RSTART 2400        // row_start[100000]
#define OFF_REND   102400      // row_end[100000]
#define OFF_BT     202400      // bf16 table, 3.2M words = 12.8 MB
#define OFF_SORTED 3402400     // u64[NNZ] = 25.6 MB (byte off 13609600, 8B-aligned)

// ---------------------------------------------------------------------------
// 0) fp32 -> packed bf16 (RNE) table conversion
// ---------------------------------------------------------------------------
__global__ void tobf16_kernel(const float2* __restrict__ in, unsigned int* __restrict__ out) {
    int i = blockIdx.x * blockDim.x + threadIdx.x;
    const int n = MEDNUM * FEATDIM / 2;
    if (i >= n) return;
    float2 f = in[i];
    unsigned int a = __float_as_uint(f.x);
    unsigned int b = __float_as_uint(f.y);
    a = (a + 0x7fffu + ((a >> 16) & 1u)) >> 16;
    b = (b + 0x7fffu + ((b >> 16) & 1u)) >> 16;
    out[i] = a | (b << 16);
}

// ---------------------------------------------------------------------------
// 1) bucket histogram: LDS-local then one atomic per (block,bucket)
// ---------------------------------------------------------------------------
__global__ __launch_bounds__(256) void histb_kernel(const int* __restrict__ row_idx,
                                                    int* __restrict__ cntb) {
    __shared__ int h[NBUCK];
    for (int i = threadIdx.x; i < NBUCK; i += 256) h[i] = 0;
    __syncthreads();
    int stride = gridDim.x * 256;
    for (int e = blockIdx.x * 256 + threadIdx.x; e < NNZ; e += stride) {
        int r = __builtin_nontemporal_load(row_idx + e);
        int fr = (r >= MEDNUM) ? r - MEDNUM : r;
        atomicAdd(&h[fr >> 6], 1);
    }
    __syncthreads();
    for (int i = threadIdx.x; i < NBUCK; i += 256)
        if (h[i]) atomicAdd(&cntb[i], h[i]);
}

// ---------------------------------------------------------------------------
// 2) scan bucket counts -> bucket_base, init cursors (single block)
// ---------------------------------------------------------------------------
__global__ __launch_bounds__(1024) void scanb_kernel(const int* __restrict__ cntb,
                                                     int* __restrict__ bbase,
                                                     int* __restrict__ cur) {
    __shared__ int sc[1024];
    int t = threadIdx.x;
    int v = (t < NBUCK) ? cntb[t] : 0;
    sc[t] = v;
    __syncthreads();
    for (int o = 1; o < 1024; o <<= 1) {
        int x = (t >= o) ? sc[t - o] : 0;
        __syncthreads();
        sc[t] += x;
        __syncthreads();
    }
    if (t < NBUCK) { int b = sc[t] - v; bbase[t] = b; cur[t] = b; }
    if (t == 0) bbase[NBUCK] = NNZ;
}

// ---------------------------------------------------------------------------
// 3) partition edges into buckets. Per-block LDS count -> one global
//    atomicAdd per (block,bucket) -> direct writes at gbase+lrank.
//    A (block,bucket) run (~16 recs = 128 B) is written within microseconds,
//    so L2 merges lines (no sparse-line eviction).
//    Record u64: [63:32]=val bits, [22:16]=rib (row-in-bucket|half<<6), [15:0]=col
// ---------------------------------------------------------------------------
__global__ __launch_bounds__(1024) void part_kernel(const float* __restrict__ vals,
                                                    const int* __restrict__ row_idx,
                                                    const int* __restrict__ col_idx,
                                                    int* __restrict__ cur,
                                                    long long* __restrict__ sorted) {
    __shared__ int cnt[NBUCK];
    __shared__ int gbase[NBUCK];
    int tid = threadIdx.x;
    int base = blockIdx.x * PART_N;
    for (int i = tid; i < NBUCK; i += 1024) cnt[i] = 0;
    __syncthreads();

    long long rec[PART_K];
    unsigned int meta[PART_K];   // bkt<<20 | lrank
#pragma unroll
    for (int k = 0; k < PART_K; k++) {
        int j = k * 1024 + tid;
        meta[k] = 0xffffffffu;
        rec[k] = 0;
        if (j < PART_N) {
            int e = base + j;
            int r = __builtin_nontemporal_load(row_idx + e);
            int c = __builtin_nontemporal_load(col_idx + e);
            float v = __builtin_nontemporal_load(vals + e);
            int half = 0;
            if (r >= MEDNUM) { r -= MEDNUM; half = 1; }
            if (c >= MEDNUM) c -= MEDNUM;
            int bkt = r >> 6;
            int rib = (r & 63) | (half << 6);
            rec[k] = ((long long)__float_as_int(v) << 32) |
                     (long long)((unsigned)(rib << 16) | (unsigned)c);
            int lr = atomicAdd(&cnt[bkt], 1);
            meta[k] = ((unsigned)bkt << 20) | (unsigned)lr;
        }
    }
    __syncthreads();
    for (int i = tid; i < NBUCK; i += 1024)
        gbase[i] = cnt[i] ? atomicAdd(&cur[i], cnt[i]) : 0;
    __syncthreads();
#pragma unroll
    for (int k = 0; k < PART_K; k++) {
        if (meta[k] != 0xffffffffu) {
            int bkt = (int)(meta[k] >> 20);
            int lr  = (int)(meta[k] & 0xfffff);
            sorted[(long long)gbase[bkt] + lr] = rec[k];
        }
    }
}

// ---------------------------------------------------------------------------
// 4) in-LDS counting sort of each bucket by rib; emits exact per-row CSR
//    bounds (row_start/row_end) and writes the bucket back in sorted order
//    (in-place, block-private range, fully coalesced lines).
// ---------------------------------------------------------------------------
__global__ __launch_bounds__(256) void bsort_kernel(const int* __restrict__ bbase,
                                                    long long* __restrict__ sorted,
                                                    int* __restrict__ row_start,
                                                    int* __restrict__ row_end) {
    __shared__ long long st[SORT_CAP];
    __shared__ int cnt[128], off[128], sc[128];
    int b = blockIdx.x, tid = threadIdx.x;
    int gs = bbase[b], ge = bbase[b + 1];
    int n = ge - gs;
    if (n > SORT_CAP) n = SORT_CAP;   // statistically impossible; avoid OOB

    if (tid < 128) cnt[tid] = 0;
    __syncthreads();

    long long rec[SORT_K];
    int rk[SORT_K];
#pragma unroll
    for (int k = 0; k < SORT_K; k++) {
        int j = k * 256 + tid;
        if (j < n) {
            rec[k] = sorted[gs + j];
            int rib = (int)((rec[k] >> 16) & 127);
            rk[k] = atomicAdd(&cnt[rib], 1);
        }
    }
    __syncthreads();
    // exclusive scan of 128 bins
    if (tid < 128) sc[tid] = cnt[tid];
    __syncthreads();
    for (int o = 1; o < 128; o <<= 1) {
        int v = 0;
        if (tid < 128 && tid >= o) v = sc[tid - o];
        __syncthreads();
        if (tid < 128 && tid >= o) sc[tid] += v;
        __syncthreads();
    }
    if (tid < 128) off[tid] = sc[tid] - cnt[tid];
    __syncthreads();
    // per-row CSR bounds
    if (tid < 128) {
        int fr0 = b * 64 + (tid & 63);
        if (fr0 < MEDNUM) {
            int r = fr0 + (tid >> 6) * MEDNUM;
            row_start[r] = gs + off[tid];
            row_end[r]   = gs + off[tid] + cnt[tid];
        }
    }
    // place sorted
#pragma unroll
    for (int k = 0; k < SORT_K; k++) {
        int j = k * 256 + tid;
        if (j < n) {
            int rib = (int)((rec[k] >> 16) & 127);
            st[off[rib] + rk[k]] = rec[k];
        }
    }
    __syncthreads();
    // coalesced writeback
#pragma unroll
    for (int k = 0; k < SORT_K; k++) {
        int j = k * 256 + tid;
        if (j < n) sorted[gs + j] = st[j];
    }
}

// ---------------------------------------------------------------------------
// 5) aggregate: one wave per folded row pair (m, m+MEDNUM); register
//    accumulation; 8-deep unroll for gather MLP; fused epilogue.
// ---------------------------------------------------------------------------
__device__ __forceinline__ void row_accum(int s, int e,
                                          const long long* __restrict__ sorted,
                                          const unsigned int* __restrict__ bt,
                                          int lane, float& ax, float& ay) {
    int i = s;
    for (; i + 8 <= e; i += 8) {
        long long p[8];
        unsigned int w[8];
#pragma unroll
        for (int k = 0; k < 8; k++) p[k] = __builtin_nontemporal_load(sorted + i + k);
#pragma unroll
        for (int k = 0; k < 8; k++) {
            int c = (int)(p[k] & 0xffff);
            w[k] = bt[(long long)c * 64 + lane];
        }
#pragma unroll
        for (int k = 0; k < 8; k++) {
            float v = __int_as_float((int)(p[k] >> 32));
            ax += v * __uint_as_float(w[k] << 16);
            ay += v * __uint_as_float(w[k] & 0xffff0000u);
        }
    }
    for (; i < e; i++) {
        long long p = __builtin_nontemporal_load(sorted + i);
        int c = (int)(p & 0xffff);
        unsigned int w = bt[(long long)c * 64 + lane];
        float v = __int_as_float((int)(p >> 32));
        ax += v * __uint_as_float(w << 16);
        ay += v * __uint_as_float(w & 0xffff0000u);
    }
}

__global__ __launch_bounds__(256) void agg_kernel(const int* __restrict__ row_start,
                                                  const int* __restrict__ row_end,
                                                  const long long* __restrict__ sorted,
                                                  const unsigned int* __restrict__ bt,
                                                  const float* __restrict__ inter,
                                                  float* __restrict__ out) {
    int wave = (blockIdx.x * blockDim.x + threadIdx.x) >> 6;
    int lane = threadIdx.x & 63;
    if (wave >= MEDNUM) return;
    int m = wave;

    float a1x = 0.f, a1y = 0.f, a2x = 0.f, a2y = 0.f;
    row_accum(row_start[m], row_end[m], sorted, bt, lane, a1x, a1y);
    row_accum(row_start[m + MEDNUM], row_end[m + MEDNUM], sorted, bt, lane, a2x, a2y);

    float t = inter[0];
    float s1 = 2.f * t;
    float s2 = 2.f * (1.f - t);
    float2 o;
    o.x = s1 * fmaxf(a1x, 0.f) + s2 * fmaxf(a2x, 0.f);
    o.y = s1 * fmaxf(a1y, 0.f) + s2 * fmaxf(a2y, 0.f);
    *(float2*)(out + (long long)m * FEATDIM + lane * 2) = o;
}

extern "C" void kernel_launch(void* const* d_in, const int* in_sizes, int n_in,
                              void* d_out, int out_size, void* d_ws, size_t ws_size,
                              hipStream_t stream) {
    const float* vals    = (const float*)d_in[0];
    const float* mEmbed  = (const float*)d_in[1];
    const float* inter   = (const float*)d_in[2];
    const int*   row_idx = (const int*)d_in[3];
    const int*   col_idx = (const int*)d_in[4];
    float* out = (float*)d_out;

    int* ws = (int*)d_ws;
    int* cntb      = ws + OFF_CNTB;
    int* bbase     = ws + OFF_BASE;
    int* cur       = ws + OFF_CUR;
    int* row_start = ws + OFF_RSTART;
    int* row_end   = ws + OFF_REND;
    unsigned int* bt = (unsigned int*)(ws + OFF_BT);
    long long* sorted = (long long*)(ws + OFF_SORTED);

    tobf16_kernel<<<(MEDNUM * FEATDIM / 2 + 255) / 256, 256, 0, stream>>>(
        (const float2*)mEmbed, bt);
    hipMemsetAsync(cntb, 0, NBUCK * sizeof(int), stream);
    histb_kernel<<<512, 256, 0, stream>>>(row_idx, cntb);
    scanb_kernel<<<1, 1024, 0, stream>>>(cntb, bbase, cur);
    part_kernel<<<PART_BLOCKS, 1024, 0, stream>>>(vals, row_idx, col_idx, cur, sorted);
    bsort_kernel<<<NBUCK, 256, 0, stream>>>(bbase, sorted, row_start, row_end);
    agg_kernel<<<(MEDNUM * 64 + 255) / 256, 256, 0, stream>>>(
        row_start, row_end, sorted, bt, inter, out);
}